// Round 8
// baseline (1121.157 us; speedup 1.0000x reference)
//
#include <hip/hip_runtime.h>

// ResidualVQ on MI355X — split-fp16 MFMA, round 8: 2 blocks/CU overlap.
// x [8,2048,512] f32, codebooks [8,1024,512] f32.
// d_out (float*): quantized [8388608], indices [131072], expired [8], losses [8].
//
// r = h + m (fp16 split), dot = hH + hM + mH into one fp32 acc (mM ~1e-6).
// d = c2 - 2*dot (r2 per-row const). Round-8: BM 64->32, LDS 139.5->72 KB
// -> 2 blocks/CU (4 waves/SIMD) so the two blocks' GEMM/argmin/update phases
// overlap across pipes (round-7 accounting showed near-zero overlap:
// MFMA 60K + LDS 40K + VALU 33K + L2 37K ~= 205K wall per CU-stage).
// Per-wave tile ct=2/mt=2, 4 col-passes: same col visit order, same
// accumulation order as round 7 -> bit-identical argmin path.

typedef _Float16 half8 __attribute__((ext_vector_type(8)));
typedef float f32x4 __attribute__((ext_vector_type(4)));

constexpr int DD = 512;
constexpr int KK = 1024;
constexpr int QQ = 8;
constexpr int NROWS = 16384;
constexpr int BM = 32;
constexpr int NBLK = NROWS / BM;   // 512
constexpr int NT = 512;            // 8 waves

__global__ void tail_init(float* __restrict__ tail) {
  if (threadIdx.x < 16) tail[threadIdx.x] = 0.0f;
}
__global__ void tail_fin(float* __restrict__ loss) {
  if (threadIdx.x < QQ) loss[threadIdx.x] *= (1.0f / 8388608.0f);
}

// ---- B-split + c2 precompute. Packed layout per code (1024 halfs):
//      [kc(16)][h(32 halfs) | m(32 halfs)],  kc = k/32.
__global__ __launch_bounds__(256) void prep_kernel(
    const float* __restrict__ cb, _Float16* __restrict__ Bpk,
    float* __restrict__ c2g) {
  const int code = blockIdx.x * 4 + (threadIdx.x >> 6);   // 0..8191
  const int lane = threadIdx.x & 63;
  const float4* p = reinterpret_cast<const float4*>(cb + (size_t)code * DD + lane * 8);
  float4 a = p[0], b = p[1];
  float v[8] = {a.x,a.y,a.z,a.w,b.x,b.y,b.z,b.w};
  half8 h, m;
  float s = 0.f;
  #pragma unroll
  for (int i = 0; i < 8; ++i) {
    _Float16 hi = (_Float16)v[i];
    h[i] = hi;
    m[i] = (_Float16)(v[i] - (float)hi);   // unscaled low split
    s += v[i] * v[i];
  }
  _Float16* dst = Bpk + (size_t)code * 1024 + (lane >> 2) * 64 + (lane & 3) * 8;
  *reinterpret_cast<half8*>(dst) = h;
  *reinterpret_cast<half8*>(dst + 32) = m;
  #pragma unroll
  for (int o = 32; o > 0; o >>= 1) s += __shfl_down(s, o, 64);
  if (lane == 0) c2g[code] = s;
}

// ---- Main fused 8-stage kernel: writes indices + loss only ----
__global__ __launch_bounds__(NT, 4) void rvq_mfma(
    const float* __restrict__ x, const float* __restrict__ cb,
    const _Float16* __restrict__ Bpk, const float* __restrict__ c2g,
    float* __restrict__ outIdx, float* __restrict__ outLoss) {
  extern __shared__ char smem[];
  // ash: [2 splits][32 rows][512 k] fp16, XOR-swizzled: 65536 B
  char* ash = smem;
  float* c2s = reinterpret_cast<float*>(smem + 65536);    // 1024 f
  float* bD  = c2s + KK;                                  // 256 f
  int*   bI  = reinterpret_cast<int*>(bD + 256);          // 256 i
  int*   fI  = bI + 256;                                  // 32 i

  const int tid  = threadIdx.x;
  const int lane = tid & 63;
  const int wv   = tid >> 6;
  const int lq   = lane >> 4;          // k-quarter within MFMA fragment
  const int cl   = lane & 15;          // col/row-within-tile lane part
  const int rowBase = blockIdx.x * BM;
  const int row = tid >> 4;            // 0..31 (staging/update ownership)
  const int seg = tid & 15;            // 32-k chunk

  auto aAddr = [&](int split, int r, int k) -> char* {
    return ash + split * 32768 + (((r << 10) + (k << 1)) ^ ((r & 7) << 4));
  };

  // ---- Prologue: residual = x -> (h,m) fp16 splits in LDS ----
  {
    const float4* xp = reinterpret_cast<const float4*>(
        x + (size_t)(rowBase + row) * DD + seg * 32);
    #pragma unroll
    for (int g = 0; g < 4; ++g) {
      float4 a = xp[2*g], b = xp[2*g+1];
      float v[8] = {a.x,a.y,a.z,a.w,b.x,b.y,b.z,b.w};
      half8 h, m;
      #pragma unroll
      for (int i = 0; i < 8; ++i) {
        _Float16 hi = (_Float16)v[i];
        h[i] = hi;
        m[i] = (_Float16)(v[i] - (float)hi);
      }
      const int k0 = seg * 32 + g * 8;
      *reinterpret_cast<half8*>(aAddr(0, row, k0)) = h;
      *reinterpret_cast<half8*>(aAddr(1, row, k0)) = m;
    }
  }

  for (int q = 0; q < QQ; ++q) {
    // stage c2 -> LDS (NT=512 threads cover KK=1024 in two strides)
    c2s[tid]       = c2g[q * KK + tid];
    c2s[tid + 512] = c2g[q * KK + tid + 512];
    __syncthreads();   // also orders prev-stage LDS A-writes vs GEMM reads

    const _Float16* Bq = Bpk + (size_t)q * KK * 1024;

    float bestD[8];
    int   bestC[8];
    #pragma unroll
    for (int s = 0; s < 8; ++s) { bestD[s] = 3.0e38f; bestC[s] = 0; }

    #pragma unroll 1
    for (int pass = 0; pass < 4; ++pass) {
      const int colTile = wv * 128 + pass * 32;   // + ct*16 + cl

      f32x4 acc[2][2];
      #pragma unroll
      for (int ct = 0; ct < 2; ++ct)
        #pragma unroll
        for (int mt = 0; mt < 2; ++mt) acc[ct][mt] = (f32x4){0.f,0.f,0.f,0.f};

      auto loadB = [&](int kc, half8 (&bh)[2], half8 (&bm)[2]) {
        #pragma unroll
        for (int ct = 0; ct < 2; ++ct) {
          const _Float16* bp = Bq + (size_t)(colTile + ct*16 + cl) * 1024
                               + kc * 64 + lq * 8;
          bh[ct] = *reinterpret_cast<const half8*>(bp);
          bm[ct] = *reinterpret_cast<const half8*>(bp + 32);
        }
      };
      auto loadA = [&](int kc, half8 (&ah)[2], half8 (&am)[2]) {
        const int k0 = kc * 32 + lq * 8;
        #pragma unroll
        for (int mt = 0; mt < 2; ++mt) {
          const int r = mt * 16 + cl;
          ah[mt] = *reinterpret_cast<const half8*>(aAddr(0, r, k0));
          am[mt] = *reinterpret_cast<const half8*>(aAddr(1, r, k0));
        }
      };
      auto mm = [&](half8 (&ah)[2], half8 (&am)[2],
                    half8 (&bh)[2], half8 (&bm)[2]) {
        #pragma unroll
        for (int ct = 0; ct < 2; ++ct)
          #pragma unroll
          for (int mt = 0; mt < 2; ++mt) {
            acc[ct][mt] = __builtin_amdgcn_mfma_f32_16x16x32_f16(ah[mt], bh[ct], acc[ct][mt], 0, 0, 0);
            acc[ct][mt] = __builtin_amdgcn_mfma_f32_16x16x32_f16(ah[mt], bm[ct], acc[ct][mt], 0, 0, 0);
            acc[ct][mt] = __builtin_amdgcn_mfma_f32_16x16x32_f16(am[mt], bh[ct], acc[ct][mt], 0, 0, 0);
          }
      };

      half8 bh0[2], bm0[2], bh1[2], bm1[2], ah[2], am[2];
      loadB(0, bh0, bm0);                     // prologue prefetch
      #pragma unroll 1
      for (int kc2 = 0; kc2 < 8; ++kc2) {
        const int kc = kc2 * 2;
        loadB(kc + 1, bh1, bm1);              // prefetch next while computing
        loadA(kc, ah, am);
        mm(ah, am, bh0, bm0);
        loadB(kc + 2 < 16 ? kc + 2 : 15, bh0, bm0);  // tail clamp (harmless)
        loadA(kc + 1, ah, am);
        mm(ah, am, bh1, bm1);
      }

      // distances for this pass (cols ascending: pass-major, ct-minor)
      #pragma unroll
      for (int ct = 0; ct < 2; ++ct) {
        const int col = colTile + ct * 16 + cl;
        const float c2v = c2s[col];
        #pragma unroll
        for (int mt = 0; mt < 2; ++mt) {
          #pragma unroll
          for (int r = 0; r < 4; ++r) {
            const float d = c2v - 2.0f * acc[ct][mt][r];
            const int s = mt * 4 + r;
            if (d < bestD[s]) { bestD[s] = d; bestC[s] = col; }
          }
        }
      }
    }

    // cross-lane argmin within 16-lane col groups (tie -> lower col)
    #pragma unroll
    for (int s = 0; s < 8; ++s) {
      #pragma unroll
      for (int xm = 1; xm <= 8; xm <<= 1) {
        const float od = __shfl_xor(bestD[s], xm, 64);
        const int   oc = __shfl_xor(bestC[s], xm, 64);
        if (od < bestD[s] || (od == bestD[s] && oc < bestC[s])) {
          bestD[s] = od; bestC[s] = oc;
        }
      }
    }
    if ((lane & 15) == 0) {
      #pragma unroll
      for (int s = 0; s < 8; ++s) {
        const int rl = (s >> 2) * 16 + lq * 4 + (s & 3);   // mt*16 + lq*4 + r
        bD[wv * 32 + rl] = bestD[s];
        bI[wv * 32 + rl] = bestC[s];
      }
    }
    __syncthreads();
    // cross-wave (ascending col ranges, strict < keeps first occurrence)
    if (tid < BM) {
      float best = bD[tid];
      int bi = bI[tid];
      #pragma unroll
      for (int w = 1; w < 8; ++w) {
        const float dw = bD[w * 32 + tid];
        if (dw < best) { best = dw; bi = bI[w * 32 + tid]; }
      }
      fI[tid] = bi;
      outIdx[(size_t)(rowBase + tid) * QQ + q] = (float)bi;
    }
    __syncthreads();

    // ---- Update: r -= codebook[idx]; re-split; loss += r_new^2 ----
    {
      const int myI = fI[row];
      const float4* cp = reinterpret_cast<const float4*>(
          cb + ((size_t)q * KK + myI) * DD + seg * 32);
      float4 cv[8];
      #pragma unroll
      for (int j = 0; j < 8; ++j) cv[j] = cp[j];   // hoist all loads
      float s2 = 0.f;
      #pragma unroll
      for (int g = 0; g < 4; ++g) {
        const int k0 = seg * 32 + g * 8;
        half8 h = *reinterpret_cast<const half8*>(aAddr(0, row, k0));
        half8 m = *reinterpret_cast<const half8*>(aAddr(1, row, k0));
        float4 ca = cv[2*g], cb4 = cv[2*g+1];
        float c[8] = {ca.x,ca.y,ca.z,ca.w,cb4.x,cb4.y,cb4.z,cb4.w};
        half8 nh, nm;
        #pragma unroll
        for (int i = 0; i < 8; ++i) {
          const float r0 = (float)h[i] + (float)m[i];
          const float rn = r0 - c[i];
          s2 += rn * rn;
          _Float16 hi = (_Float16)rn;
          nh[i] = hi;
          nm[i] = (_Float16)(rn - (float)hi);
        }
        *reinterpret_cast<half8*>(aAddr(0, row, k0)) = nh;
        *reinterpret_cast<half8*>(aAddr(1, row, k0)) = nm;
      }
      #pragma unroll
      for (int o = 32; o > 0; o >>= 1) s2 += __shfl_down(s2, o, 64);
      if (lane == 0) atomicAdd(outLoss + q, s2);
    }
    // no trailing barrier: next stage's c2 barrier orders these LDS writes
  }
}

// ---- Reconstruction: quantized_out = sum_q codebook[q][idx_q] (np order) ----
__global__ __launch_bounds__(256) void recon_kernel(
    const float* __restrict__ cb, const float* __restrict__ outIdx,
    float* __restrict__ outQ) {
  const int row = blockIdx.x * 4 + (threadIdx.x >> 6);
  const int lane = threadIdx.x & 63;
  const int d0 = lane * 8;
  float o[8] = {0,0,0,0,0,0,0,0};
  #pragma unroll
  for (int q = 0; q < QQ; ++q) {
    const int idx = (int)outIdx[(size_t)row * QQ + q];
    const float4* cp = reinterpret_cast<const float4*>(
        cb + ((size_t)q * KK + idx) * DD + d0);
    float4 a = cp[0], b = cp[1];
    o[0] += a.x; o[1] += a.y; o[2] += a.z; o[3] += a.w;
    o[4] += b.x; o[5] += b.y; o[6] += b.z; o[7] += b.w;
  }
  float4* op = reinterpret_cast<float4*>(outQ + (size_t)row * DD + d0);
  op[0] = make_float4(o[0], o[1], o[2], o[3]);
  op[1] = make_float4(o[4], o[5], o[6], o[7]);
}

extern "C" void kernel_launch(void* const* d_in, const int* in_sizes, int n_in,
                              void* d_out, int out_size, void* d_ws, size_t ws_size,
                              hipStream_t stream) {
  const float* x  = (const float*)d_in[0];
  const float* cb = (const float*)d_in[1];

  float* out     = (float*)d_out;
  float* outQ    = out;
  float* outIdx  = out + (size_t)NROWS * DD;        // 8388608
  float* tail    = outIdx + (size_t)NROWS * QQ;     // expired[8], losses[8]
  float* outLoss = tail + QQ;

  // scratch inside outQ region (recon overwrites it at the end):
  _Float16* Bpk = (_Float16*)outQ;                  // 8192 codes * 1024 halfs
  float*    c2g = outQ + 4300800;                   // past Bpk (4.2M floats)

  const size_t shmem = 65536 + 4096 + 1024 + 1024 + 128;  // 71808 B
  (void)hipFuncSetAttribute((const void*)rvq_mfma,
                            hipFuncAttributeMaxDynamicSharedMemorySize,
                            (int)shmem);

  tail_init<<<1, 64, 0, stream>>>(tail);
  prep_kernel<<<(QQ * KK) / 4, 256, 0, stream>>>(cb, Bpk, c2g);
  rvq_mfma<<<NBLK, NT, shmem, stream>>>(x, cb, Bpk, c2g, outIdx, outLoss);
  recon_kernel<<<NROWS / 4, 256, 0, stream>>>(cb, outIdx, outQ);
  tail_fin<<<1, 64, 0, stream>>>(outLoss);
}

// Round 9
// 775.169 us; speedup vs baseline: 1.4463x; 1.4463x over previous
//
#include <hip/hip_runtime.h>

// ResidualVQ on MI355X — split-fp16 MFMA, round 9: schedule pinning.
// x [8,2048,512] f32, codebooks [8,1024,512] f32.
// d_out (float*): quantized [8388608], indices [131072], expired [8], losses [8].
//
// r = h + m (fp16 split), dot = hH + hM + mH into one fp32 acc (mM ~1e-6).
// d = c2 - 2*dot (r2 per-row const). Geometry = round 7 (BM=64, NT=512,
// 1 block/CU, ct=4/mt=4, 2 col passes).
// Round-9: r7/r8 PMC showed MfmaUtil*wall == required pipe time (~53K cyc)
// => pipe never contended, waves fail to feed it; r8's VGPR=60 proves the
// compiler serialized the B double-buffer (sunk loads to use). Fix:
// sched_group_barrier pins per half-kc: [8 VMEM_READ][8 DS_READ][48 MFMA],
// forcing prefetch liveness; mm reordered split-major (16 indep MFMAs per
// burst, per-acc order unchanged -> bit-identical argmin).

typedef _Float16 half8 __attribute__((ext_vector_type(8)));
typedef float f32x4 __attribute__((ext_vector_type(4)));

constexpr int DD = 512;
constexpr int KK = 1024;
constexpr int QQ = 8;
constexpr int NROWS = 16384;
constexpr int BM = 64;
constexpr int NBLK = NROWS / BM;   // 256
constexpr int NT = 512;            // 8 waves

__global__ void tail_init(float* __restrict__ tail) {
  if (threadIdx.x < 16) tail[threadIdx.x] = 0.0f;
}
__global__ void tail_fin(float* __restrict__ loss) {
  if (threadIdx.x < QQ) loss[threadIdx.x] *= (1.0f / 8388608.0f);
}

// ---- B-split + c2 precompute. Packed layout per code (1024 halfs):
//      [kc(16)][h(32 halfs) | m(32 halfs)],  kc = k/32.
__global__ __launch_bounds__(256) void prep_kernel(
    const float* __restrict__ cb, _Float16* __restrict__ Bpk,
    float* __restrict__ c2g) {
  const int code = blockIdx.x * 4 + (threadIdx.x >> 6);   // 0..8191
  const int lane = threadIdx.x & 63;
  const float4* p = reinterpret_cast<const float4*>(cb + (size_t)code * DD + lane * 8);
  float4 a = p[0], b = p[1];
  float v[8] = {a.x,a.y,a.z,a.w,b.x,b.y,b.z,b.w};
  half8 h, m;
  float s = 0.f;
  #pragma unroll
  for (int i = 0; i < 8; ++i) {
    _Float16 hi = (_Float16)v[i];
    h[i] = hi;
    m[i] = (_Float16)(v[i] - (float)hi);   // unscaled low split
    s += v[i] * v[i];
  }
  _Float16* dst = Bpk + (size_t)code * 1024 + (lane >> 2) * 64 + (lane & 3) * 8;
  *reinterpret_cast<half8*>(dst) = h;
  *reinterpret_cast<half8*>(dst + 32) = m;
  #pragma unroll
  for (int o = 32; o > 0; o >>= 1) s += __shfl_down(s, o, 64);
  if (lane == 0) c2g[code] = s;
}

// ---- Main fused 8-stage kernel: writes indices + loss only ----
__global__ __launch_bounds__(NT, 2) void rvq_mfma(
    const float* __restrict__ x, const float* __restrict__ cb,
    const _Float16* __restrict__ Bpk, const float* __restrict__ c2g,
    float* __restrict__ outIdx, float* __restrict__ outLoss) {
  extern __shared__ char smem[];
  // ash: [2 splits][64 rows][512 k] fp16, XOR-swizzled: 131072 B
  char* ash = smem;
  float* c2s = reinterpret_cast<float*>(smem + 131072);   // 1024 f
  float* bD  = c2s + KK;                                  // 512 f
  int*   bI  = reinterpret_cast<int*>(bD + NT);           // 512 i
  int*   fI  = bI + NT;                                   // 64 i

  const int tid  = threadIdx.x;
  const int lane = tid & 63;
  const int wv   = tid >> 6;
  const int lq   = lane >> 4;          // k-quarter within MFMA fragment
  const int cl   = lane & 15;          // col/row-within-tile lane part
  const int rowBase = blockIdx.x * BM;
  const int row = tid >> 3;            // 0..63 (staging/update ownership)
  const int seg = tid & 7;             // 64-k chunk

  auto aAddr = [&](int split, int r, int k) -> char* {
    return ash + split * 65536 + (((r << 10) + (k << 1)) ^ ((r & 7) << 4));
  };

  // ---- Prologue: residual = x -> (h,m) fp16 splits in LDS ----
  {
    const float4* xp = reinterpret_cast<const float4*>(
        x + (size_t)(rowBase + row) * DD + seg * 64);
    #pragma unroll
    for (int g = 0; g < 8; ++g) {
      float4 a = xp[2*g], b = xp[2*g+1];
      float v[8] = {a.x,a.y,a.z,a.w,b.x,b.y,b.z,b.w};
      half8 h, m;
      #pragma unroll
      for (int i = 0; i < 8; ++i) {
        _Float16 hi = (_Float16)v[i];
        h[i] = hi;
        m[i] = (_Float16)(v[i] - (float)hi);
      }
      const int k0 = seg * 64 + g * 8;
      *reinterpret_cast<half8*>(aAddr(0, row, k0)) = h;
      *reinterpret_cast<half8*>(aAddr(1, row, k0)) = m;
    }
  }

  for (int q = 0; q < QQ; ++q) {
    // stage c2 -> LDS (NT=512 threads cover KK=1024 in two strides)
    c2s[tid]       = c2g[q * KK + tid];
    c2s[tid + 512] = c2g[q * KK + tid + 512];
    __syncthreads();   // also orders prev-stage LDS A-writes vs GEMM reads

    const _Float16* Bq = Bpk + (size_t)q * KK * 1024;

    float bestD[16];
    int   bestC[16];
    #pragma unroll
    for (int s = 0; s < 16; ++s) { bestD[s] = 3.0e38f; bestC[s] = 0; }

    #pragma unroll 1
    for (int pass = 0; pass < 2; ++pass) {
      const int colTile = wv * 128 + pass * 64;   // + ct*16 + cl

      f32x4 acc[4][4];
      #pragma unroll
      for (int ct = 0; ct < 4; ++ct)
        #pragma unroll
        for (int mt = 0; mt < 4; ++mt) acc[ct][mt] = (f32x4){0.f,0.f,0.f,0.f};

      auto loadB = [&](int kc, half8 (&bh)[4], half8 (&bm)[4]) {
        #pragma unroll
        for (int ct = 0; ct < 4; ++ct) {
          const _Float16* bp = Bq + (size_t)(colTile + ct*16 + cl) * 1024
                               + kc * 64 + lq * 8;
          bh[ct] = *reinterpret_cast<const half8*>(bp);
          bm[ct] = *reinterpret_cast<const half8*>(bp + 32);
        }
      };
      auto loadA = [&](int kc, half8 (&ah)[4], half8 (&am)[4]) {
        const int k0 = kc * 32 + lq * 8;
        #pragma unroll
        for (int mt = 0; mt < 4; ++mt) {
          const int r = mt * 16 + cl;
          ah[mt] = *reinterpret_cast<const half8*>(aAddr(0, r, k0));
          am[mt] = *reinterpret_cast<const half8*>(aAddr(1, r, k0));
        }
      };
      // split-major: 16 independent hH, then 16 hM, then 16 mH.
      // Per-acc sequence still hH -> hM -> mH (bit-identical results).
      auto mm = [&](half8 (&ah)[4], half8 (&am)[4],
                    half8 (&bh)[4], half8 (&bm)[4]) {
        #pragma unroll
        for (int ct = 0; ct < 4; ++ct)
          #pragma unroll
          for (int mt = 0; mt < 4; ++mt)
            acc[ct][mt] = __builtin_amdgcn_mfma_f32_16x16x32_f16(ah[mt], bh[ct], acc[ct][mt], 0, 0, 0);
        #pragma unroll
        for (int ct = 0; ct < 4; ++ct)
          #pragma unroll
          for (int mt = 0; mt < 4; ++mt)
            acc[ct][mt] = __builtin_amdgcn_mfma_f32_16x16x32_f16(ah[mt], bm[ct], acc[ct][mt], 0, 0, 0);
        #pragma unroll
        for (int ct = 0; ct < 4; ++ct)
          #pragma unroll
          for (int mt = 0; mt < 4; ++mt)
            acc[ct][mt] = __builtin_amdgcn_mfma_f32_16x16x32_f16(am[mt], bh[ct], acc[ct][mt], 0, 0, 0);
      };
      // Pin emitted order: 8 B-prefetch loads, 8 A ds_reads, 48 MFMA.
      auto pin = [&]() {
        __builtin_amdgcn_sched_group_barrier(0x020, 8, 0);   // VMEM_READ
        __builtin_amdgcn_sched_group_barrier(0x100, 8, 0);   // DS_READ
        __builtin_amdgcn_sched_group_barrier(0x008, 48, 0);  // MFMA
      };

      half8 bh0[4], bm0[4], bh1[4], bm1[4], ah[4], am[4];
      loadB(0, bh0, bm0);                     // prologue prefetch
      #pragma unroll 1
      for (int kc2 = 0; kc2 < 8; ++kc2) {
        const int kc = kc2 * 2;
        loadB(kc + 1, bh1, bm1);              // prefetch next
        loadA(kc, ah, am);
        mm(ah, am, bh0, bm0);
        pin();
        loadB(kc + 2 < 16 ? kc + 2 : 15, bh0, bm0);  // tail clamp (harmless)
        loadA(kc + 1, ah, am);
        mm(ah, am, bh1, bm1);
        pin();
      }

      // distances for this pass (cols ascending: pass-major, ct-minor)
      #pragma unroll
      for (int ct = 0; ct < 4; ++ct) {
        const int col = colTile + ct * 16 + cl;
        const float c2v = c2s[col];
        #pragma unroll
        for (int mt = 0; mt < 4; ++mt) {
          #pragma unroll
          for (int r = 0; r < 4; ++r) {
            const float d = c2v - 2.0f * acc[ct][mt][r];
            const int s = mt * 4 + r;
            if (d < bestD[s]) { bestD[s] = d; bestC[s] = col; }
          }
        }
      }
    }

    // cross-lane argmin within 16-lane col groups (tie -> lower col)
    #pragma unroll
    for (int s = 0; s < 16; ++s) {
      #pragma unroll
      for (int xm = 1; xm <= 8; xm <<= 1) {
        const float od = __shfl_xor(bestD[s], xm, 64);
        const int   oc = __shfl_xor(bestC[s], xm, 64);
        if (od < bestD[s] || (od == bestD[s] && oc < bestC[s])) {
          bestD[s] = od; bestC[s] = oc;
        }
      }
    }
    if ((lane & 15) == 0) {
      #pragma unroll
      for (int s = 0; s < 16; ++s) {
        const int rl = (s >> 2) * 16 + lq * 4 + (s & 3);
        bD[wv * 64 + rl] = bestD[s];
        bI[wv * 64 + rl] = bestC[s];
      }
    }
    __syncthreads();
    // cross-wave (ascending col ranges, strict < keeps first occurrence)
    if (tid < BM) {
      float best = bD[tid];
      int bi = bI[tid];
      #pragma unroll
      for (int w = 1; w < 8; ++w) {
        const float dw = bD[w * 64 + tid];
        if (dw < best) { best = dw; bi = bI[w * 64 + tid]; }
      }
      fI[tid] = bi;
      outIdx[(size_t)(rowBase + tid) * QQ + q] = (float)bi;
    }
    __syncthreads();

    // ---- Update: r -= codebook[idx]; re-split; loss += r_new^2 ----
    {
      const int myI = fI[row];
      const float4* cp = reinterpret_cast<const float4*>(
          cb + ((size_t)q * KK + myI) * DD + seg * 64);
      float4 cv[16];
      #pragma unroll
      for (int j = 0; j < 16; ++j) cv[j] = cp[j];   // hoist all loads
      float s2 = 0.f;
      #pragma unroll
      for (int g = 0; g < 8; ++g) {
        const int k0 = seg * 64 + g * 8;
        half8 h = *reinterpret_cast<const half8*>(aAddr(0, row, k0));
        half8 m = *reinterpret_cast<const half8*>(aAddr(1, row, k0));
        float4 ca = cv[2*g], cb4 = cv[2*g+1];
        float c[8] = {ca.x,ca.y,ca.z,ca.w,cb4.x,cb4.y,cb4.z,cb4.w};
        half8 nh, nm;
        #pragma unroll
        for (int i = 0; i < 8; ++i) {
          const float r0 = (float)h[i] + (float)m[i];
          const float rn = r0 - c[i];
          s2 += rn * rn;
          _Float16 hi = (_Float16)rn;
          nh[i] = hi;
          nm[i] = (_Float16)(rn - (float)hi);
        }
        *reinterpret_cast<half8*>(aAddr(0, row, k0)) = nh;
        *reinterpret_cast<half8*>(aAddr(1, row, k0)) = nm;
      }
      #pragma unroll
      for (int o = 32; o > 0; o >>= 1) s2 += __shfl_down(s2, o, 64);
      if (lane == 0) atomicAdd(outLoss + q, s2);
    }
    // no trailing barrier: next stage's c2 barrier orders these LDS writes
  }
}

// ---- Reconstruction: quantized_out = sum_q codebook[q][idx_q] (np order) ----
__global__ __launch_bounds__(256) void recon_kernel(
    const float* __restrict__ cb, const float* __restrict__ outIdx,
    float* __restrict__ outQ) {
  const int row = blockIdx.x * 4 + (threadIdx.x >> 6);
  const int lane = threadIdx.x & 63;
  const int d0 = lane * 8;
  float o[8] = {0,0,0,0,0,0,0,0};
  #pragma unroll
  for (int q = 0; q < QQ; ++q) {
    const int idx = (int)outIdx[(size_t)row * QQ + q];
    const float4* cp = reinterpret_cast<const float4*>(
        cb + ((size_t)q * KK + idx) * DD + d0);
    float4 a = cp[0], b = cp[1];
    o[0] += a.x; o[1] += a.y; o[2] += a.z; o[3] += a.w;
    o[4] += b.x; o[5] += b.y; o[6] += b.z; o[7] += b.w;
  }
  float4* op = reinterpret_cast<float4*>(outQ + (size_t)row * DD + d0);
  op[0] = make_float4(o[0], o[1], o[2], o[3]);
  op[1] = make_float4(o[4], o[5], o[6], o[7]);
}

extern "C" void kernel_launch(void* const* d_in, const int* in_sizes, int n_in,
                              void* d_out, int out_size, void* d_ws, size_t ws_size,
                              hipStream_t stream) {
  const float* x  = (const float*)d_in[0];
  const float* cb = (const float*)d_in[1];

  float* out     = (float*)d_out;
  float* outQ    = out;
  float* outIdx  = out + (size_t)NROWS * DD;        // 8388608
  float* tail    = outIdx + (size_t)NROWS * QQ;     // expired[8], losses[8]
  float* outLoss = tail + QQ;

  // scratch inside outQ region (recon overwrites it at the end):
  _Float16* Bpk = (_Float16*)outQ;                  // 8192 codes * 1024 halfs
  float*    c2g = outQ + 4300800;                   // past Bpk (4.2M floats)

  const size_t shmem = 131072 + 4096 + 2048 + 2048 + 256;  // 139520 B
  (void)hipFuncSetAttribute((const void*)rvq_mfma,
                            hipFuncAttributeMaxDynamicSharedMemorySize,
                            (int)shmem);

  tail_init<<<1, 64, 0, stream>>>(tail);
  prep_kernel<<<(QQ * KK) / 4, 256, 0, stream>>>(cb, Bpk, c2g);
  rvq_mfma<<<NBLK, NT, shmem, stream>>>(x, cb, Bpk, c2g, outIdx, outLoss);
  recon_kernel<<<NROWS / 4, 256, 0, stream>>>(cb, outIdx, outQ);
  tail_fin<<<1, 64, 0, stream>>>(outLoss);
}